// Round 4
// baseline (1470.620 us; speedup 1.0000x reference)
//
#include <hip/hip_runtime.h>
#include <math.h>

#define DIM   1024
#define HALF  512
#define NROWS 65536

// ============================ FUSED PATH =================================
// One persistent cooperative kernel: 1024 blocks x 256 threads.
// Global sync = two-level tree barrier (32 leaves x 32 blocks -> 32-ary root).
// Round-3 evidence: a FLAT 1024-arrival barrier costs ~140 us (same-address
// device-scope atomic RMWs serialize at ~130 ns each at the coherence point);
// the tree cuts per-address arrivals to 32 -> ~10 us per barrier.
// Every level is self-resetting (count back to 0 before gen bump, release-
// ordered), and waiters compare against a sampled gen -> replay-safe under
// rocprof dispatch replay (round-2 hang root cause was monotonic counters).
#define GRID  1024
#define RPB   (NROWS / GRID)   // 64 rows per block

// fused workspace layout (float offsets)
#define FOFF_QACC  0                       // [512]
#define FOFF_PVEC  (FOFF_QACC + HALF)      // [1024]
#define FOFF_PSTAT (FOFF_PVEC + DIM)       // float2[GRID]
#define FOFF_ESUM  (FOFF_PSTAT + 2*GRID)   // [GRID]
#define FOFF_WACC  (FOFF_ESUM + GRID)      // [1024]
#define FOFF_OV    (FOFF_WACC + DIM)       // [1024]
#define FOFF_PW    (FOFF_OV + DIM)         // [GRID*DIM] = 4 MB
#define FOFF_BAR   (FOFF_PW + GRID*DIM)    // barrier ints (memset to 0 once)

#define NLEAF       32
#define LEAF_STRIDE 16                     // ints => 64 B per leaf cacheline
#define ROOT_COUNT  (NLEAF * LEAF_STRIDE)        // int index 512
#define ROOT_GEN    (NLEAF * LEAF_STRIDE + 16)   // int index 528 (own line)

__device__ __forceinline__ void gbar(int* bar) {
    __syncthreads();
    if (threadIdx.x == 0) {
        __threadfence();  // publish this block's global writes device-wide
        int* lcount = &bar[(int)(blockIdx.x & (NLEAF - 1)) * LEAF_STRIDE];
        int* lgen   = lcount + 1;
        int* rcount = &bar[ROOT_COUNT];
        int* rgen   = &bar[ROOT_GEN];

        int lg = __hip_atomic_load(lgen, __ATOMIC_ACQUIRE, __HIP_MEMORY_SCOPE_AGENT);
        int v  = __hip_atomic_fetch_add(lcount, 1,
                                        __ATOMIC_ACQ_REL, __HIP_MEMORY_SCOPE_AGENT);
        if (v == GRID / NLEAF - 1) {
            // leaf leader: reset leaf count, then join the root barrier.
            __hip_atomic_store(lcount, 0,
                               __ATOMIC_RELAXED, __HIP_MEMORY_SCOPE_AGENT);
            int rg = __hip_atomic_load(rgen, __ATOMIC_ACQUIRE,
                                       __HIP_MEMORY_SCOPE_AGENT);
            int rv = __hip_atomic_fetch_add(rcount, 1,
                                            __ATOMIC_ACQ_REL, __HIP_MEMORY_SCOPE_AGENT);
            if (rv == NLEAF - 1) {
                // root leader: reset root count (release-ordered before gen bump)
                __hip_atomic_store(rcount, 0,
                                   __ATOMIC_RELAXED, __HIP_MEMORY_SCOPE_AGENT);
                __hip_atomic_fetch_add(rgen, 1,
                                       __ATOMIC_RELEASE, __HIP_MEMORY_SCOPE_AGENT);
            } else {
                long sp = 0;
                while (__hip_atomic_load(rgen, __ATOMIC_ACQUIRE,
                                         __HIP_MEMORY_SCOPE_AGENT) == rg) {
                    __builtin_amdgcn_s_sleep(4);
                    if (++sp > (1L << 22)) break;  // fail visibly, never hang
                }
            }
            // release this leaf's waiters
            __hip_atomic_fetch_add(lgen, 1,
                                   __ATOMIC_RELEASE, __HIP_MEMORY_SCOPE_AGENT);
        } else {
            long sp = 0;
            while (__hip_atomic_load(lgen, __ATOMIC_ACQUIRE,
                                     __HIP_MEMORY_SCOPE_AGENT) == lg) {
                __builtin_amdgcn_s_sleep(4);
                if (++sp > (1L << 22)) break;      // fail visibly, never hang
            }
        }
        __threadfence();  // discard stale cached lines before consuming
    }
    __syncthreads();
}

__global__ __launch_bounds__(256, 4)
void k_fused(const float* __restrict__ q_init,
             const float* __restrict__ K,
             const float* __restrict__ Wq,
             const float* __restrict__ bq,
             const float* __restrict__ Wk,
             const float* __restrict__ Wv,
             const float* __restrict__ bv,
             const float* __restrict__ Wm,
             const float* __restrict__ bm,
             const float* __restrict__ gamma,
             float* ws,
             float* out)
{
    const int t = threadIdx.x;        // 0..255
    const int b = blockIdx.x;         // 0..1023
    const int wave = t >> 6, lane = t & 63;

    float*  qacc  = ws + FOFF_QACC;
    float*  pvec  = ws + FOFF_PVEC;
    float2* pstat = (float2*)(ws + FOFF_PSTAT);
    float*  esum  = ws + FOFF_ESUM;
    float*  wacc  = ws + FOFF_WACC;
    float*  ov    = ws + FOFF_OV;
    float*  pw    = ws + FOFF_PW;
    int*    bar   = (int*)(ws + FOFF_BAR);

    __shared__ float4 sh4[256];
    __shared__ float  shA[256];
    __shared__ float  shB[256];
    __shared__ float  shq[HALF];
    __shared__ float  cf[RPB];     // coeff for this block's 64 rows
    __shared__ float  ssv[RPB];    // scores  (LDS-resident across barriers)
    __shared__ float  siv[RPB];    // 1/||k|| (LDS-resident across barriers)
    __shared__ float  bc[2];       // mean, rstd broadcast

    // ---- Phase 1: qnorm (redundant per active block) + qacc = qn @ Wq ----
    if (b < HALF / 4) {
        float v0 = q_init[t], v1 = q_init[t + 256],
              v2 = q_init[t + 512], v3 = q_init[t + 768];
        shA[t] = v0 * v0 + v1 * v1 + v2 * v2 + v3 * v3;
        __syncthreads();
        for (int s = 128; s > 0; s >>= 1) {
            if (t < s) shA[t] += shA[t + s];
            __syncthreads();
        }
        float qinv = 1.0f / fmaxf(sqrtf(shA[0]), 1e-12f);
        const float4* W4 = (const float4*)Wq;
        float vv0 = v0 * qinv, vv1 = v1 * qinv, vv2 = v2 * qinv, vv3 = v3 * qinv;
        float4 acc;
        float4 m0 = W4[(size_t)t * (HALF / 4) + b];
        float4 m1 = W4[(size_t)(t + 256) * (HALF / 4) + b];
        float4 m2 = W4[(size_t)(t + 512) * (HALF / 4) + b];
        float4 m3 = W4[(size_t)(t + 768) * (HALF / 4) + b];
        acc.x = vv0 * m0.x + vv1 * m1.x + vv2 * m2.x + vv3 * m3.x;
        acc.y = vv0 * m0.y + vv1 * m1.y + vv2 * m2.y + vv3 * m3.y;
        acc.z = vv0 * m0.z + vv1 * m1.z + vv2 * m2.z + vv3 * m3.z;
        acc.w = vv0 * m0.w + vv1 * m1.w + vv2 * m2.w + vv3 * m3.w;
        sh4[t] = acc;
        __syncthreads();
        for (int s = 128; s > 0; s >>= 1) {
            if (t < s) {
                sh4[t].x += sh4[t + s].x; sh4[t].y += sh4[t + s].y;
                sh4[t].z += sh4[t + s].z; sh4[t].w += sh4[t + s].w;
            }
            __syncthreads();
        }
        if (t == 0) ((float4*)qacc)[b] = sh4[0];
    }
    gbar(bar);

    // ---- Phase 2: pvec[d] = Wk[d,:] . (qacc + bq), one wave per row ----
    if (b < DIM / 4) {
        for (int j = t; j < HALF; j += 256) shq[j] = qacc[j] + bq[j];
        __syncthreads();
        int d = b * 4 + wave;
        const float* row = Wk + (size_t)d * HALF;
        float acc = 0.f;
        #pragma unroll
        for (int j0 = 0; j0 < HALF; j0 += 64) acc += row[j0 + lane] * shq[j0 + lane];
        #pragma unroll
        for (int o = 32; o > 0; o >>= 1) acc += __shfl_down(acc, o);
        if (lane == 0) pvec[d] = acc;
    }
    gbar(bar);

    // ---- Phase 3: pass 1 — scores + inv-norms (kept in LDS) + block stats ----
    {
        sh4[t] = ((const float4*)pvec)[t];
        __syncthreads();
        float bsum = 0.f, bssq = 0.f;   // meaningful on lane 0 of each wave
        #pragma unroll 1
        for (int it = 0; it < 4; ++it) {
            const int row0 = b * 64 + it * 16 + wave * 4;
            const float4* k4 = (const float4*)K + (size_t)row0 * 256;
            float d0 = 0.f, d1 = 0.f, d2 = 0.f, d3 = 0.f;
            float q0 = 0.f, q1 = 0.f, q2 = 0.f, q3 = 0.f;
            #pragma unroll
            for (int i = 0; i < 4; ++i) {
                const int idx = lane + i * 64;
                float4 p = sh4[idx];
                float4 a = k4[idx];
                float4 bb = k4[256 + idx];
                float4 c = k4[512 + idx];
                float4 e = k4[768 + idx];
                d0 += a.x * p.x + a.y * p.y + a.z * p.z + a.w * p.w;
                q0 += a.x * a.x + a.y * a.y + a.z * a.z + a.w * a.w;
                d1 += bb.x * p.x + bb.y * p.y + bb.z * p.z + bb.w * p.w;
                q1 += bb.x * bb.x + bb.y * bb.y + bb.z * bb.z + bb.w * bb.w;
                d2 += c.x * p.x + c.y * p.y + c.z * p.z + c.w * p.w;
                q2 += c.x * c.x + c.y * c.y + c.z * c.z + c.w * c.w;
                d3 += e.x * p.x + e.y * p.y + e.z * p.z + e.w * p.w;
                q3 += e.x * e.x + e.y * e.y + e.z * e.z + e.w * e.w;
            }
            #pragma unroll
            for (int o = 32; o > 0; o >>= 1) {
                d0 += __shfl_down(d0, o); q0 += __shfl_down(q0, o);
                d1 += __shfl_down(d1, o); q1 += __shfl_down(q1, o);
                d2 += __shfl_down(d2, o); q2 += __shfl_down(q2, o);
                d3 += __shfl_down(d3, o); q3 += __shfl_down(q3, o);
            }
            if (lane == 0) {
                float i0 = 1.0f / fmaxf(sqrtf(q0), 1e-12f);
                float i1 = 1.0f / fmaxf(sqrtf(q1), 1e-12f);
                float i2 = 1.0f / fmaxf(sqrtf(q2), 1e-12f);
                float i3 = 1.0f / fmaxf(sqrtf(q3), 1e-12f);
                float s0 = d0 * i0, s1 = d1 * i1, s2 = d2 * i2, s3 = d3 * i3;
                const int o64 = it * 16 + wave * 4;
                ssv[o64] = s0; ssv[o64 + 1] = s1; ssv[o64 + 2] = s2; ssv[o64 + 3] = s3;
                siv[o64] = i0; siv[o64 + 1] = i1; siv[o64 + 2] = i2; siv[o64 + 3] = i3;
                bsum += s0 + s1 + s2 + s3;
                bssq += s0 * s0 + s1 * s1 + s2 * s2 + s3 * s3;
            }
        }
        if (lane == 0) { shA[wave] = bsum; shB[wave] = bssq; }
        __syncthreads();
        if (t == 0)
            pstat[b] = make_float2(shA[0] + shA[1] + shA[2] + shA[3],
                                   shB[0] + shB[1] + shB[2] + shB[3]);
    }
    gbar(bar);

    // ---- Phase 4+5: redundant global stats + coeff (LDS) + pass-2 partials ----
    {
        float s = 0.f, q = 0.f;
        #pragma unroll
        for (int i = 0; i < 4; ++i) {
            float2 p = pstat[t + i * 256];
            s += p.x; q += p.y;
        }
        shA[t] = s; shB[t] = q;
        __syncthreads();
        for (int k = 128; k > 0; k >>= 1) {
            if (t < k) { shA[t] += shA[t + k]; shB[t] += shB[t + k]; }
            __syncthreads();
        }
        if (t == 0) {
            float mean = shA[0] / (float)NROWS;
            float var  = (shB[0] - (float)NROWS * mean * mean) / (float)(NROWS - 1);
            bc[0] = mean;
            bc[1] = 1.0f / (sqrtf(fmaxf(var, 0.0f)) + 1e-8f);
        }
        __syncthreads();
        float mean = bc[0], rstd = bc[1];
        if (t < RPB) {
            float z = (ssv[t] - mean) * rstd;
            z = fminf(fmaxf(z, -10.0f), 10.0f);
            float e = expf(z);
            cf[t] = e * siv[t];
            float es = e;
            #pragma unroll
            for (int o = 32; o > 0; o >>= 1) es += __shfl_down(es, o);
            if (t == 0) esum[b] = es;
        }
        __syncthreads();
        const float4* M4 = (const float4*)K + (size_t)(b * 64) * 256 + t;
        float4 acc = make_float4(0.f, 0.f, 0.f, 0.f);
        #pragma unroll 16
        for (int r = 0; r < RPB; ++r) {
            float c = cf[r];
            float4 m = M4[(size_t)r * 256];
            acc.x += c * m.x; acc.y += c * m.y; acc.z += c * m.z; acc.w += c * m.w;
        }
        ((float4*)pw)[(size_t)b * 256 + t] = acc;
    }
    gbar(bar);

    // ---- Phase 6: fold 1024 partials + normalize by sum(exp) -> wacc ----
    if (b < 256) {
        float es = esum[t] + esum[t + 256] + esum[t + 512] + esum[t + 768];
        shA[t] = es;
        __syncthreads();
        for (int s = 128; s > 0; s >>= 1) {
            if (t < s) shA[t] += shA[t + s];
            __syncthreads();
        }
        float inv = 1.0f / shA[0];
        const float4* pw4 = (const float4*)pw;
        float4 acc = make_float4(0.f, 0.f, 0.f, 0.f);
        #pragma unroll
        for (int j = 0; j < 4; ++j) {
            float4 m = pw4[(size_t)(t + j * 256) * 256 + b];
            acc.x += m.x; acc.y += m.y; acc.z += m.z; acc.w += m.w;
        }
        sh4[t] = acc;
        __syncthreads();
        for (int s = 128; s > 0; s >>= 1) {
            if (t < s) {
                sh4[t].x += sh4[t + s].x; sh4[t].y += sh4[t + s].y;
                sh4[t].z += sh4[t + s].z; sh4[t].w += sh4[t + s].w;
            }
            __syncthreads();
        }
        if (t == 0) {
            float4 w = sh4[0];
            ((float4*)wacc)[b] = make_float4(w.x * inv, w.y * inv, w.z * inv, w.w * inv);
        }
    }
    gbar(bar);

    // ---- Phase 7: ov = wacc @ Wv ----
    if (b < 256) {
        const float4* W4 = (const float4*)Wv;
        float4 acc = make_float4(0.f, 0.f, 0.f, 0.f);
        for (int r = t; r < DIM; r += 256) {
            float c = wacc[r];
            float4 m = W4[(size_t)r * 256 + b];
            acc.x += c * m.x; acc.y += c * m.y; acc.z += c * m.z; acc.w += c * m.w;
        }
        sh4[t] = acc;
        __syncthreads();
        for (int s = 128; s > 0; s >>= 1) {
            if (t < s) {
                sh4[t].x += sh4[t + s].x; sh4[t].y += sh4[t + s].y;
                sh4[t].z += sh4[t + s].z; sh4[t].w += sh4[t + s].w;
            }
            __syncthreads();
        }
        if (t == 0) ((float4*)ov)[b] = sh4[0];
    }
    gbar(bar);

    // ---- Phase 8: outacc = (ov + bv) @ Wm, fused final gate ----
    if (b < 256) {
        const float4* W4 = (const float4*)Wm;
        float4 acc = make_float4(0.f, 0.f, 0.f, 0.f);
        for (int r = t; r < DIM; r += 256) {
            float c = ov[r] + bv[r];
            float4 m = W4[(size_t)r * 256 + b];
            acc.x += c * m.x; acc.y += c * m.y; acc.z += c * m.z; acc.w += c * m.w;
        }
        sh4[t] = acc;
        __syncthreads();
        for (int s = 128; s > 0; s >>= 1) {
            if (t < s) {
                sh4[t].x += sh4[t + s].x; sh4[t].y += sh4[t + s].y;
                sh4[t].z += sh4[t + s].z; sh4[t].w += sh4[t + s].w;
            }
            __syncthreads();
        }
        if (t == 0) {
            float g = 1.0f / (1.0f + expf(-gamma[0]));
            float4 o  = sh4[0];
            float4 qi = ((const float4*)q_init)[b];
            float4 bb = ((const float4*)bm)[b];
            float4 res;
            res.x = g * qi.x + (1.0f - g) * (o.x + bb.x);
            res.y = g * qi.y + (1.0f - g) * (o.y + bb.y);
            res.z = g * qi.z + (1.0f - g) * (o.z + bb.z);
            res.w = g * qi.w + (1.0f - g) * (o.w + bb.w);
            ((float4*)out)[b] = res;
        }
    }
}

// ====================== FALLBACK PATH (proven baseline) ======================
#define SBLK 4096
#define WBLK 1024
#define WF1  32

#define OFF_QN     0
#define OFF_QACC   (OFF_QN + DIM)
#define OFF_PVEC   (OFF_QACC + HALF)
#define OFF_SCAL   (OFF_PVEC + DIM)
#define OFF_PSTAT  (OFF_SCAL + 8)
#define OFF_S      (OFF_PSTAT + 2*SBLK)
#define OFF_INVN   (OFF_S + NROWS)
#define OFF_COEFF  (OFF_INVN + NROWS)
#define OFF_ESUM   (OFF_COEFF + NROWS)
#define OFF_PW     (OFF_ESUM + 256)
#define OFF_P2     (OFF_PW + WBLK*DIM)
#define OFF_WACC   (OFF_P2 + WF1*DIM)
#define OFF_OVACC  (OFF_WACC + DIM)
#define OFF_OUTACC (OFF_OVACC + DIM)

__global__ void k_qnorm(const float* __restrict__ q_init, float* __restrict__ qn) {
    __shared__ float red[1024];
    int t = threadIdx.x;
    float v = q_init[t];
    red[t] = v * v;
    __syncthreads();
    for (int s = 512; s > 0; s >>= 1) {
        if (t < s) red[t] += red[t + s];
        __syncthreads();
    }
    float inv = 1.0f / fmaxf(sqrtf(red[0]), 1e-12f);
    qn[t] = v * inv;
}

__global__ void k_matvec_col(const float* __restrict__ M,
                             const float* __restrict__ coeff,
                             const float* __restrict__ cbias,
                             float* __restrict__ out,
                             int nrows, int ncols4) {
    __shared__ float4 red[256];
    int t = threadIdx.x, c4 = blockIdx.x;
    const float4* M4 = (const float4*)M;
    float4 acc = make_float4(0.f, 0.f, 0.f, 0.f);
    for (int r = t; r < nrows; r += 256) {
        float c = coeff[r];
        if (cbias) c += cbias[r];
        float4 m = M4[(size_t)r * ncols4 + c4];
        acc.x += c * m.x; acc.y += c * m.y; acc.z += c * m.z; acc.w += c * m.w;
    }
    red[t] = acc;
    __syncthreads();
    for (int s = 128; s > 0; s >>= 1) {
        if (t < s) {
            red[t].x += red[t + s].x; red[t].y += red[t + s].y;
            red[t].z += red[t + s].z; red[t].w += red[t + s].w;
        }
        __syncthreads();
    }
    if (t == 0) ((float4*)out)[c4] = red[0];
}

__global__ void k_pvec(const float* __restrict__ Wk,
                       const float* __restrict__ qacc,
                       const float* __restrict__ bq,
                       float* __restrict__ pvec) {
    __shared__ float q[HALF];
    int t = threadIdx.x;
    for (int j = t; j < HALF; j += 256) q[j] = qacc[j] + bq[j];
    __syncthreads();
    int wave = t >> 6, lane = t & 63;
    int d = blockIdx.x * 4 + wave;
    const float* row = Wk + (size_t)d * HALF;
    float acc = 0.f;
    #pragma unroll
    for (int j0 = 0; j0 < HALF; j0 += 64) acc += row[j0 + lane] * q[j0 + lane];
    #pragma unroll
    for (int o = 32; o > 0; o >>= 1) acc += __shfl_down(acc, o);
    if (lane == 0) pvec[d] = acc;
}

__global__ void k_scores(const float* __restrict__ K,
                         const float* __restrict__ pvec,
                         float* __restrict__ svals,
                         float* __restrict__ invn,
                         float2* __restrict__ pstat) {
    __shared__ float4 p4s[256];
    __shared__ float wsum[4], wssq[4];
    int t = threadIdx.x;
    p4s[t] = ((const float4*)pvec)[t];
    __syncthreads();
    int wave = t >> 6, lane = t & 63;
    int row0 = blockIdx.x * 16 + wave * 4;
    const float4* k4 = (const float4*)K + (size_t)row0 * 256;
    float d0 = 0, d1 = 0, d2 = 0, d3 = 0;
    float q0 = 0, q1 = 0, q2 = 0, q3 = 0;
    #pragma unroll
    for (int i = 0; i < 4; ++i) {
        int idx = lane + i * 64;
        float4 p = p4s[idx];
        float4 a = k4[idx];
        float4 b = k4[256 + idx];
        float4 c = k4[512 + idx];
        float4 e = k4[768 + idx];
        d0 += a.x * p.x + a.y * p.y + a.z * p.z + a.w * p.w;
        q0 += a.x * a.x + a.y * a.y + a.z * a.z + a.w * a.w;
        d1 += b.x * p.x + b.y * p.y + b.z * p.z + b.w * p.w;
        q1 += b.x * b.x + b.y * b.y + b.z * b.z + b.w * b.w;
        d2 += c.x * p.x + c.y * p.y + c.z * p.z + c.w * p.w;
        q2 += c.x * c.x + c.y * c.y + c.z * c.z + c.w * c.w;
        d3 += e.x * p.x + e.y * p.y + e.z * p.z + e.w * p.w;
        q3 += e.x * e.x + e.y * e.y + e.z * e.z + e.w * e.w;
    }
    #pragma unroll
    for (int o = 32; o > 0; o >>= 1) {
        d0 += __shfl_down(d0, o); q0 += __shfl_down(q0, o);
        d1 += __shfl_down(d1, o); q1 += __shfl_down(q1, o);
        d2 += __shfl_down(d2, o); q2 += __shfl_down(q2, o);
        d3 += __shfl_down(d3, o); q3 += __shfl_down(q3, o);
    }
    if (lane == 0) {
        float i0 = 1.0f / fmaxf(sqrtf(q0), 1e-12f);
        float i1 = 1.0f / fmaxf(sqrtf(q1), 1e-12f);
        float i2 = 1.0f / fmaxf(sqrtf(q2), 1e-12f);
        float i3 = 1.0f / fmaxf(sqrtf(q3), 1e-12f);
        float s0 = d0 * i0, s1 = d1 * i1, s2 = d2 * i2, s3 = d3 * i3;
        float4 sv = make_float4(s0, s1, s2, s3);
        float4 iv = make_float4(i0, i1, i2, i3);
        *(float4*)(svals + row0) = sv;
        *(float4*)(invn + row0) = iv;
        wsum[wave] = s0 + s1 + s2 + s3;
        wssq[wave] = s0 * s0 + s1 * s1 + s2 * s2 + s3 * s3;
    }
    __syncthreads();
    if (t == 0)
        pstat[blockIdx.x] = make_float2(wsum[0] + wsum[1] + wsum[2] + wsum[3],
                                        wssq[0] + wssq[1] + wssq[2] + wssq[3]);
}

__global__ void k_redstats(const float2* __restrict__ pstat, float* __restrict__ scal) {
    __shared__ float rs[1024], rq[1024];
    int t = threadIdx.x;
    float s = 0.f, q = 0.f;
    for (int i = t; i < SBLK; i += 1024) {
        float2 p = pstat[i];
        s += p.x; q += p.y;
    }
    rs[t] = s; rq[t] = q;
    __syncthreads();
    for (int k = 512; k > 0; k >>= 1) {
        if (t < k) { rs[t] += rs[t + k]; rq[t] += rq[t + k]; }
        __syncthreads();
    }
    if (t == 0) {
        float mean = rs[0] / (float)NROWS;
        float var  = (rq[0] - (float)NROWS * mean * mean) / (float)(NROWS - 1);
        scal[0] = mean;
        scal[1] = 1.0f / (sqrtf(fmaxf(var, 0.0f)) + 1e-8f);
    }
}

__global__ void k_coeff(const float* __restrict__ svals,
                        const float* __restrict__ invn,
                        const float* __restrict__ scal,
                        float* __restrict__ coeff,
                        float* __restrict__ esum) {
    __shared__ float red[256];
    int t = threadIdx.x;
    int i = blockIdx.x * 256 + t;
    float mean = scal[0], rstd = scal[1];
    float z = (svals[i] - mean) * rstd;
    z = fminf(fmaxf(z, -10.0f), 10.0f);
    float e = expf(z);
    coeff[i] = e * invn[i];
    red[t] = e;
    __syncthreads();
    for (int s = 128; s > 0; s >>= 1) {
        if (t < s) red[t] += red[t + s];
        __syncthreads();
    }
    if (t == 0) esum[blockIdx.x] = red[0];
}

__global__ void k_wsum(const float* __restrict__ K,
                       const float* __restrict__ coeff,
                       float* __restrict__ pw) {
    int t = threadIdx.x;
    int r0 = blockIdx.x * 64;
    const float4* M4 = (const float4*)K + (size_t)r0 * 256 + t;
    const float* cfp = coeff + r0;
    float4 acc = make_float4(0.f, 0.f, 0.f, 0.f);
    #pragma unroll 16
    for (int r = 0; r < 64; ++r) {
        float c = cfp[r];
        float4 m = M4[(size_t)r * 256];
        acc.x += c * m.x; acc.y += c * m.y; acc.z += c * m.z; acc.w += c * m.w;
    }
    ((float4*)pw)[(size_t)blockIdx.x * 256 + t] = acc;
}

__global__ void k_wfold(const float* __restrict__ pw, float* __restrict__ p2) {
    int t = threadIdx.x, b = blockIdx.x;
    const float4* pw4 = (const float4*)pw;
    float4 acc = make_float4(0.f, 0.f, 0.f, 0.f);
    #pragma unroll
    for (int p = 0; p < WBLK / WF1; ++p) {
        float4 m = pw4[(size_t)(b * (WBLK / WF1) + p) * 256 + t];
        acc.x += m.x; acc.y += m.y; acc.z += m.z; acc.w += m.w;
    }
    ((float4*)p2)[b * 256 + t] = acc;
}

__global__ void k_wreduce(const float* __restrict__ p2,
                          const float* __restrict__ esum,
                          float* __restrict__ wacc) {
    __shared__ float red[256];
    int t = threadIdx.x;
    if (t < 256) red[t] = esum[t];
    __syncthreads();
    for (int s = 128; s > 0; s >>= 1) {
        if (t < s) red[t] += red[t + s];
        __syncthreads();
    }
    float inv = 1.0f / red[0];
    float acc = 0.f;
    #pragma unroll
    for (int b = 0; b < WF1; ++b) acc += p2[b * DIM + t];
    wacc[t] = acc * inv;
}

__global__ void k_final(const float* __restrict__ q_init,
                        const float* __restrict__ outacc,
                        const float* __restrict__ bm,
                        const float* __restrict__ gamma,
                        float* __restrict__ out) {
    int t = threadIdx.x;
    float g = 1.0f / (1.0f + expf(-gamma[0]));
    out[t] = g * q_init[t] + (1.0f - g) * (outacc[t] + bm[t]);
}

// ================================ LAUNCH =====================================
extern "C" void kernel_launch(void* const* d_in, const int* in_sizes, int n_in,
                              void* d_out, int out_size, void* d_ws, size_t ws_size,
                              hipStream_t stream) {
    const float* q_init = (const float*)d_in[0];
    const float* k_init = (const float*)d_in[1];
    const float* Wq     = (const float*)d_in[2];
    const float* bq     = (const float*)d_in[3];
    const float* Wk     = (const float*)d_in[4];
    // d_in[5] = bk: constant shift of all scores -> cancels in standardization
    const float* Wv     = (const float*)d_in[6];
    const float* bv     = (const float*)d_in[7];
    const float* Wm     = (const float*)d_in[8];
    const float* bm     = (const float*)d_in[9];
    const float* gamma  = (const float*)d_in[10];
    float* out = (float*)d_out;
    float* ws  = (float*)d_ws;

    // belt-and-braces: known barrier state even after an aborted prior run
    hipMemsetAsync(ws + FOFF_BAR, 0, 4096, stream);

    void* args[] = { (void*)&q_init, (void*)&k_init, (void*)&Wq, (void*)&bq,
                     (void*)&Wk, (void*)&Wv, (void*)&bv, (void*)&Wm,
                     (void*)&bm, (void*)&gamma, (void*)&ws, (void*)&out };
    hipError_t err = hipLaunchCooperativeKernel(k_fused, dim3(GRID), dim3(256),
                                                args, 0, stream);
    if (err == hipSuccess) return;

    // ---- fallback: proven 12-kernel baseline ----
    float*  qn     = ws + OFF_QN;
    float*  qacc   = ws + OFF_QACC;
    float*  pvec   = ws + OFF_PVEC;
    float*  scal   = ws + OFF_SCAL;
    float2* pstat  = (float2*)(ws + OFF_PSTAT);
    float*  svals  = ws + OFF_S;
    float*  invn   = ws + OFF_INVN;
    float*  coeff  = ws + OFF_COEFF;
    float*  esum   = ws + OFF_ESUM;
    float*  pw     = ws + OFF_PW;
    float*  p2     = ws + OFF_P2;
    float*  wacc   = ws + OFF_WACC;
    float*  ovacc  = ws + OFF_OVACC;
    float*  outacc = ws + OFF_OUTACC;

    k_qnorm<<<1, 1024, 0, stream>>>(q_init, qn);
    k_matvec_col<<<HALF / 4, 256, 0, stream>>>(Wq, qn, nullptr, qacc, DIM, HALF / 4);
    k_pvec<<<DIM / 4, 256, 0, stream>>>(Wk, qacc, bq, pvec);
    k_scores<<<SBLK, 256, 0, stream>>>(k_init, pvec, svals, invn, pstat);
    k_redstats<<<1, 1024, 0, stream>>>(pstat, scal);
    k_coeff<<<NROWS / 256, 256, 0, stream>>>(svals, invn, scal, coeff, esum);
    k_wsum<<<WBLK, 256, 0, stream>>>(k_init, coeff, pw);
    k_wfold<<<WF1, 256, 0, stream>>>(pw, p2);
    k_wreduce<<<1, 1024, 0, stream>>>(p2, esum, wacc);
    k_matvec_col<<<DIM / 4, 256, 0, stream>>>(Wv, wacc, nullptr, ovacc, DIM, DIM / 4);
    k_matvec_col<<<DIM / 4, 256, 0, stream>>>(Wm, ovacc, bv, outacc, DIM, DIM / 4);
    k_final<<<1, 1024, 0, stream>>>(q_init, outacc, bm, gamma, out);
}

// Round 6
// 477.106 us; speedup vs baseline: 3.0824x; 3.0824x over previous
//
#include <hip/hip_runtime.h>
#include <math.h>

#define DIM   1024
#define HALF  512
#define NROWS 65536
#define SBLK  4096   // k_scores blocks (16 rows each)
#define WBLK  1024   // k_wsum blocks (64 rows each)

// ---- workspace layout (float offsets), all atomic-free, no memset needed ----
#define OFF_QACC   0
#define OFF_PVEC   (OFF_QACC + HALF)
#define OFF_PSTAT  (OFF_PVEC + DIM)          // float2[SBLK]
#define OFF_S      (OFF_PSTAT + 2*SBLK)
#define OFF_INVN   (OFF_S + NROWS)
#define OFF_COEFF  (OFF_INVN + NROWS)
#define OFF_ESUM   (OFF_COEFF + NROWS)       // [256]
#define OFF_PW     (OFF_ESUM + 256)          // [WBLK*DIM] = 4 MB
#define OFF_WACC   (OFF_PW + WBLK*DIM)
#define OFF_OVACC  (OFF_WACC + DIM)
#define OFF_END    (OFF_OVACC + DIM)

// qnorm (redundant per block) + qacc = qn @ Wq. 128 blocks x 256 thr.
// Body lifted from the fused Phase 1 (verified absmax=0 in rounds 3/4).
__global__ void k_q(const float* __restrict__ q_init,
                    const float* __restrict__ Wq,
                    float* __restrict__ qacc) {
    __shared__ float  shA[256];
    __shared__ float4 sh4[256];
    int t = threadIdx.x, b = blockIdx.x;
    float v0 = q_init[t], v1 = q_init[t + 256],
          v2 = q_init[t + 512], v3 = q_init[t + 768];
    shA[t] = v0 * v0 + v1 * v1 + v2 * v2 + v3 * v3;
    __syncthreads();
    for (int s = 128; s > 0; s >>= 1) {
        if (t < s) shA[t] += shA[t + s];
        __syncthreads();
    }
    float qinv = 1.0f / fmaxf(sqrtf(shA[0]), 1e-12f);
    const float4* W4 = (const float4*)Wq;
    float vv0 = v0 * qinv, vv1 = v1 * qinv, vv2 = v2 * qinv, vv3 = v3 * qinv;
    float4 m0 = W4[(size_t)t * (HALF / 4) + b];
    float4 m1 = W4[(size_t)(t + 256) * (HALF / 4) + b];
    float4 m2 = W4[(size_t)(t + 512) * (HALF / 4) + b];
    float4 m3 = W4[(size_t)(t + 768) * (HALF / 4) + b];
    float4 acc;
    acc.x = vv0 * m0.x + vv1 * m1.x + vv2 * m2.x + vv3 * m3.x;
    acc.y = vv0 * m0.y + vv1 * m1.y + vv2 * m2.y + vv3 * m3.y;
    acc.z = vv0 * m0.z + vv1 * m1.z + vv2 * m2.z + vv3 * m3.z;
    acc.w = vv0 * m0.w + vv1 * m1.w + vv2 * m2.w + vv3 * m3.w;
    sh4[t] = acc;
    __syncthreads();
    for (int s = 128; s > 0; s >>= 1) {
        if (t < s) {
            sh4[t].x += sh4[t + s].x; sh4[t].y += sh4[t + s].y;
            sh4[t].z += sh4[t + s].z; sh4[t].w += sh4[t + s].w;
        }
        __syncthreads();
    }
    if (t == 0) ((float4*)qacc)[b] = sh4[0];
}

// pvec[d] = sum_j Wk[d][j] * (qacc[j] + bq[j]); one wave per row d. (round-0 proven)
__global__ void k_pvec(const float* __restrict__ Wk,
                       const float* __restrict__ qacc,
                       const float* __restrict__ bq,
                       float* __restrict__ pvec) {
    __shared__ float q[HALF];
    int t = threadIdx.x; // 256
    for (int j = t; j < HALF; j += 256) q[j] = qacc[j] + bq[j];
    __syncthreads();
    int wave = t >> 6, lane = t & 63;
    int d = blockIdx.x * 4 + wave;
    const float* row = Wk + (size_t)d * HALF;
    float acc = 0.f;
    #pragma unroll
    for (int j0 = 0; j0 < HALF; j0 += 64) acc += row[j0 + lane] * q[j0 + lane];
    #pragma unroll
    for (int o = 32; o > 0; o >>= 1) acc += __shfl_down(acc, o);
    if (lane == 0) pvec[d] = acc;
}

// Pass 1: scores + inv norms + per-block (sum, ssq) partials. (round-0 proven)
__global__ void k_scores(const float* __restrict__ K,
                         const float* __restrict__ pvec,
                         float* __restrict__ svals,
                         float* __restrict__ invn,
                         float2* __restrict__ pstat) {
    __shared__ float4 p4s[256];
    __shared__ float wsum[4], wssq[4];
    int t = threadIdx.x;
    p4s[t] = ((const float4*)pvec)[t];
    __syncthreads();
    int wave = t >> 6, lane = t & 63;
    int row0 = blockIdx.x * 16 + wave * 4;
    const float4* k4 = (const float4*)K + (size_t)row0 * 256;
    float d0 = 0, d1 = 0, d2 = 0, d3 = 0;
    float q0 = 0, q1 = 0, q2 = 0, q3 = 0;
    #pragma unroll
    for (int i = 0; i < 4; ++i) {
        int idx = lane + i * 64;
        float4 p = p4s[idx];
        float4 a = k4[idx];
        float4 b = k4[256 + idx];
        float4 c = k4[512 + idx];
        float4 e = k4[768 + idx];
        d0 += a.x * p.x + a.y * p.y + a.z * p.z + a.w * p.w;
        q0 += a.x * a.x + a.y * a.y + a.z * a.z + a.w * a.w;
        d1 += b.x * p.x + b.y * p.y + b.z * p.z + b.w * p.w;
        q1 += b.x * b.x + b.y * b.y + b.z * b.z + b.w * b.w;
        d2 += c.x * p.x + c.y * p.y + c.z * p.z + c.w * p.w;
        q2 += c.x * c.x + c.y * c.y + c.z * c.z + c.w * c.w;
        d3 += e.x * p.x + e.y * p.y + e.z * p.z + e.w * p.w;
        q3 += e.x * e.x + e.y * e.y + e.z * e.z + e.w * e.w;
    }
    #pragma unroll
    for (int o = 32; o > 0; o >>= 1) {
        d0 += __shfl_down(d0, o); q0 += __shfl_down(q0, o);
        d1 += __shfl_down(d1, o); q1 += __shfl_down(q1, o);
        d2 += __shfl_down(d2, o); q2 += __shfl_down(q2, o);
        d3 += __shfl_down(d3, o); q3 += __shfl_down(q3, o);
    }
    if (lane == 0) {
        float i0 = 1.0f / fmaxf(sqrtf(q0), 1e-12f);
        float i1 = 1.0f / fmaxf(sqrtf(q1), 1e-12f);
        float i2 = 1.0f / fmaxf(sqrtf(q2), 1e-12f);
        float i3 = 1.0f / fmaxf(sqrtf(q3), 1e-12f);
        float s0 = d0 * i0, s1 = d1 * i1, s2 = d2 * i2, s3 = d3 * i3;
        float4 sv = make_float4(s0, s1, s2, s3);
        float4 iv = make_float4(i0, i1, i2, i3);
        *(float4*)(svals + row0) = sv;
        *(float4*)(invn + row0) = iv;
        wsum[wave] = s0 + s1 + s2 + s3;
        wssq[wave] = s0 * s0 + s1 * s1 + s2 * s2 + s3 * s3;
    }
    __syncthreads();
    if (t == 0)
        pstat[blockIdx.x] = make_float2(wsum[0] + wsum[1] + wsum[2] + wsum[3],
                                        wssq[0] + wssq[1] + wssq[2] + wssq[3]);
}

// Redundant global stats per block + coeff + per-block esum partial.
// 256 blocks x 256 thr. Merges the old k_redstats (1-block) into k_coeff.
__global__ void k_coeff2(const float* __restrict__ svals,
                         const float* __restrict__ invn,
                         const float2* __restrict__ pstat,
                         float* __restrict__ coeff,
                         float* __restrict__ esum) {
    __shared__ float rs[256], rq[256];
    int t = threadIdx.x, b = blockIdx.x;
    float s = 0.f, q = 0.f;
    for (int i = t; i < SBLK; i += 256) {
        float2 p = pstat[i];
        s += p.x; q += p.y;
    }
    rs[t] = s; rq[t] = q;
    __syncthreads();
    for (int k = 128; k > 0; k >>= 1) {
        if (t < k) { rs[t] += rs[t + k]; rq[t] += rq[t + k]; }
        __syncthreads();
    }
    float mean = rs[0] / (float)NROWS;
    float var  = (rq[0] - (float)NROWS * mean * mean) / (float)(NROWS - 1);
    float rstd = 1.0f / (sqrtf(fmaxf(var, 0.0f)) + 1e-8f);
    int i = b * 256 + t;
    float z = (svals[i] - mean) * rstd;
    z = fminf(fmaxf(z, -10.0f), 10.0f);
    float e = expf(z);
    coeff[i] = e * invn[i];
    __syncthreads();              // all reads of rs[0]/rq[0] done before reuse
    rs[t] = e;
    __syncthreads();
    for (int k = 128; k > 0; k >>= 1) {
        if (t < k) rs[t] += rs[t + k];
        __syncthreads();
    }
    if (t == 0) esum[b] = rs[0];
}

// Pass 2: per-block private partial column sums. (round-0 proven)
__global__ void k_wsum(const float* __restrict__ K,
                       const float* __restrict__ coeff,
                       float* __restrict__ pw) {
    int t = threadIdx.x;
    int r0 = blockIdx.x * 64;
    const float4* M4 = (const float4*)K + (size_t)r0 * 256 + t;
    const float* cf = coeff + r0;
    float4 acc = make_float4(0.f, 0.f, 0.f, 0.f);
    #pragma unroll 16
    for (int r = 0; r < 64; ++r) {
        float c = cf[r];
        float4 m = M4[(size_t)r * 256];
        acc.x += c * m.x; acc.y += c * m.y; acc.z += c * m.z; acc.w += c * m.w;
    }
    ((float4*)pw)[(size_t)blockIdx.x * 256 + t] = acc;
}

// Fold WBLK=1024 partials -> wacc = w / sum(exp). 4 blocks x 256 thr.
// Merges the old k_wfold (32 blocks) + k_wreduce (1 block).
// Thread (b, t): float4-column c4 = b*64 + (t&63); quarter q = t>>6 sums
// rows [q*256, q*256+256). Lanes 0..63 read 64 consecutive float4 -> coalesced.
__global__ void k_wred(const float* __restrict__ pw,
                       const float* __restrict__ esum,
                       float* __restrict__ wacc) {
    __shared__ float  rs[256];
    __shared__ float4 sh4[256];
    int t = threadIdx.x, b = blockIdx.x;
    rs[t] = esum[t];
    __syncthreads();
    for (int k = 128; k > 0; k >>= 1) {
        if (t < k) rs[t] += rs[t + k];
        __syncthreads();
    }
    float inv = 1.0f / rs[0];
    const float4* pw4 = (const float4*)pw;
    int c4 = b * 64 + (t & 63);
    int qr = t >> 6;
    float4 acc = make_float4(0.f, 0.f, 0.f, 0.f);
    #pragma unroll 8
    for (int p = qr * 256; p < qr * 256 + 256; ++p) {
        float4 m = pw4[(size_t)p * 256 + c4];
        acc.x += m.x; acc.y += m.y; acc.z += m.z; acc.w += m.w;
    }
    sh4[t] = acc;
    __syncthreads();
    if (t < 64) {
        float4 a = sh4[t], b4 = sh4[t + 64], c = sh4[t + 128], d = sh4[t + 192];
        float4 w;
        w.x = (a.x + b4.x + c.x + d.x) * inv;
        w.y = (a.y + b4.y + c.y + d.y) * inv;
        w.z = (a.z + b4.z + c.z + d.z) * inv;
        w.w = (a.w + b4.w + c.w + d.w) * inv;
        ((float4*)wacc)[b * 64 + t] = w;
    }
}

// out[c4] = sum_r (coeff[r] (+cbias[r])) * M[r][c4]. (round-0 proven)
__global__ void k_matvec_col(const float* __restrict__ M,
                             const float* __restrict__ coeff,
                             const float* __restrict__ cbias,
                             float* __restrict__ out,
                             int nrows, int ncols4) {
    __shared__ float4 red[256];
    int t = threadIdx.x, c4 = blockIdx.x;
    const float4* M4 = (const float4*)M;
    float4 acc = make_float4(0.f, 0.f, 0.f, 0.f);
    for (int r = t; r < nrows; r += 256) {
        float c = coeff[r];
        if (cbias) c += cbias[r];
        float4 m = M4[(size_t)r * ncols4 + c4];
        acc.x += c * m.x; acc.y += c * m.y; acc.z += c * m.z; acc.w += c * m.w;
    }
    red[t] = acc;
    __syncthreads();
    for (int s = 128; s > 0; s >>= 1) {
        if (t < s) {
            red[t].x += red[t + s].x; red[t].y += red[t + s].y;
            red[t].z += red[t + s].z; red[t].w += red[t + s].w;
        }
        __syncthreads();
    }
    if (t == 0) ((float4*)out)[c4] = red[0];
}

// outacc = (ovacc + bv) @ Wm, with the sigmoid gate fused (fused Phase-8 body).
// 256 blocks x 256 thr.
__global__ void k_mv_final(const float* __restrict__ Wm,
                           const float* __restrict__ ovacc,
                           const float* __restrict__ bv,
                           const float* __restrict__ q_init,
                           const float* __restrict__ bm,
                           const float* __restrict__ gamma,
                           float* __restrict__ out) {
    __shared__ float4 sh4[256];
    int t = threadIdx.x, b = blockIdx.x;
    const float4* W4 = (const float4*)Wm;
    float4 acc = make_float4(0.f, 0.f, 0.f, 0.f);
    for (int r = t; r < DIM; r += 256) {
        float c = ovacc[r] + bv[r];
        float4 m = W4[(size_t)r * 256 + b];
        acc.x += c * m.x; acc.y += c * m.y; acc.z += c * m.z; acc.w += c * m.w;
    }
    sh4[t] = acc;
    __syncthreads();
    for (int s = 128; s > 0; s >>= 1) {
        if (t < s) {
            sh4[t].x += sh4[t + s].x; sh4[t].y += sh4[t + s].y;
            sh4[t].z += sh4[t + s].z; sh4[t].w += sh4[t + s].w;
        }
        __syncthreads();
    }
    if (t == 0) {
        float g = 1.0f / (1.0f + expf(-gamma[0]));
        float4 o  = sh4[0];
        float4 qi = ((const float4*)q_init)[b];
        float4 bb = ((const float4*)bm)[b];
        float4 res;
        res.x = g * qi.x + (1.0f - g) * (o.x + bb.x);
        res.y = g * qi.y + (1.0f - g) * (o.y + bb.y);
        res.z = g * qi.z + (1.0f - g) * (o.z + bb.z);
        res.w = g * qi.w + (1.0f - g) * (o.w + bb.w);
        ((float4*)out)[b] = res;
    }
}

extern "C" void kernel_launch(void* const* d_in, const int* in_sizes, int n_in,
                              void* d_out, int out_size, void* d_ws, size_t ws_size,
                              hipStream_t stream) {
    const float* q_init = (const float*)d_in[0];
    const float* k_init = (const float*)d_in[1];
    const float* Wq     = (const float*)d_in[2];
    const float* bq     = (const float*)d_in[3];
    const float* Wk     = (const float*)d_in[4];
    // d_in[5] = bk: constant shift of all scores -> cancels in standardization
    const float* Wv     = (const float*)d_in[6];
    const float* bv     = (const float*)d_in[7];
    const float* Wm     = (const float*)d_in[8];
    const float* bm     = (const float*)d_in[9];
    const float* gamma  = (const float*)d_in[10];
    float* out = (float*)d_out;
    float* ws  = (float*)d_ws;

    float*  qacc   = ws + OFF_QACC;
    float*  pvec   = ws + OFF_PVEC;
    float2* pstat  = (float2*)(ws + OFF_PSTAT);
    float*  svals  = ws + OFF_S;
    float*  invn   = ws + OFF_INVN;
    float*  coeff  = ws + OFF_COEFF;
    float*  esum   = ws + OFF_ESUM;
    float*  pw     = ws + OFF_PW;
    float*  wacc   = ws + OFF_WACC;
    float*  ovacc  = ws + OFF_OVACC;

    // 8 dispatches (was 12): qnorm, redstats, wfold/wreduce, final all merged
    k_q<<<HALF / 4, 256, 0, stream>>>(q_init, Wq, qacc);
    k_pvec<<<DIM / 4, 256, 0, stream>>>(Wk, qacc, bq, pvec);
    k_scores<<<SBLK, 256, 0, stream>>>(k_init, pvec, svals, invn, pstat);
    k_coeff2<<<NROWS / 256, 256, 0, stream>>>(svals, invn, pstat, coeff, esum);
    k_wsum<<<WBLK, 256, 0, stream>>>(k_init, coeff, pw);
    k_wred<<<4, 256, 0, stream>>>(pw, esum, wacc);
    k_matvec_col<<<DIM / 4, 256, 0, stream>>>(Wv, wacc, nullptr, ovacc, DIM, DIM / 4);
    k_mv_final<<<DIM / 4, 256, 0, stream>>>(Wm, ovacc, bv, q_init, bm, gamma, out);
}

// Round 7
// 454.277 us; speedup vs baseline: 3.2373x; 1.0503x over previous
//
#include <hip/hip_runtime.h>
#include <math.h>

#define DIM   1024
#define HALF  512
#define NROWS 65536
#define SBLK  4096   // k_scores blocks (16 rows each)
#define WBLK  1024   // k_wsumc blocks (64 rows each)

// ---- workspace layout (float offsets), all atomic-free, no memset needed ----
#define OFF_QACC   0
#define OFF_PVEC   (OFF_QACC + HALF)
#define OFF_PSTAT  (OFF_PVEC + DIM)          // float2[SBLK]
#define OFF_S      (OFF_PSTAT + 2*SBLK)
#define OFF_INVN   (OFF_S + NROWS)
#define OFF_ESUM   (OFF_INVN + NROWS)        // [WBLK]
#define OFF_PW     (OFF_ESUM + WBLK)         // [WBLK*DIM] = 4 MB
#define OFF_WACC   (OFF_PW + WBLK*DIM)
#define OFF_OVACC  (OFF_WACC + DIM)
#define OFF_END    (OFF_OVACC + DIM)

// qnorm (redundant per block) + qacc = qn @ Wq. 128 blocks x 256 thr. (proven r6)
__global__ void k_q(const float* __restrict__ q_init,
                    const float* __restrict__ Wq,
                    float* __restrict__ qacc) {
    __shared__ float  shA[256];
    __shared__ float4 sh4[256];
    int t = threadIdx.x, b = blockIdx.x;
    float v0 = q_init[t], v1 = q_init[t + 256],
          v2 = q_init[t + 512], v3 = q_init[t + 768];
    shA[t] = v0 * v0 + v1 * v1 + v2 * v2 + v3 * v3;
    __syncthreads();
    for (int s = 128; s > 0; s >>= 1) {
        if (t < s) shA[t] += shA[t + s];
        __syncthreads();
    }
    float qinv = 1.0f / fmaxf(sqrtf(shA[0]), 1e-12f);
    const float4* W4 = (const float4*)Wq;
    float vv0 = v0 * qinv, vv1 = v1 * qinv, vv2 = v2 * qinv, vv3 = v3 * qinv;
    float4 m0 = W4[(size_t)t * (HALF / 4) + b];
    float4 m1 = W4[(size_t)(t + 256) * (HALF / 4) + b];
    float4 m2 = W4[(size_t)(t + 512) * (HALF / 4) + b];
    float4 m3 = W4[(size_t)(t + 768) * (HALF / 4) + b];
    float4 acc;
    acc.x = vv0 * m0.x + vv1 * m1.x + vv2 * m2.x + vv3 * m3.x;
    acc.y = vv0 * m0.y + vv1 * m1.y + vv2 * m2.y + vv3 * m3.y;
    acc.z = vv0 * m0.z + vv1 * m1.z + vv2 * m2.z + vv3 * m3.z;
    acc.w = vv0 * m0.w + vv1 * m1.w + vv2 * m2.w + vv3 * m3.w;
    sh4[t] = acc;
    __syncthreads();
    for (int s = 128; s > 0; s >>= 1) {
        if (t < s) {
            sh4[t].x += sh4[t + s].x; sh4[t].y += sh4[t + s].y;
            sh4[t].z += sh4[t + s].z; sh4[t].w += sh4[t + s].w;
        }
        __syncthreads();
    }
    if (t == 0) ((float4*)qacc)[b] = sh4[0];
}

// pvec[d] = sum_j Wk[d][j] * (qacc[j] + bq[j]); one wave per row d. (proven r0)
__global__ void k_pvec(const float* __restrict__ Wk,
                       const float* __restrict__ qacc,
                       const float* __restrict__ bq,
                       float* __restrict__ pvec) {
    __shared__ float q[HALF];
    int t = threadIdx.x; // 256
    for (int j = t; j < HALF; j += 256) q[j] = qacc[j] + bq[j];
    __syncthreads();
    int wave = t >> 6, lane = t & 63;
    int d = blockIdx.x * 4 + wave;
    const float* row = Wk + (size_t)d * HALF;
    float acc = 0.f;
    #pragma unroll
    for (int j0 = 0; j0 < HALF; j0 += 64) acc += row[j0 + lane] * q[j0 + lane];
    #pragma unroll
    for (int o = 32; o > 0; o >>= 1) acc += __shfl_down(acc, o);
    if (lane == 0) pvec[d] = acc;
}

// Pass 1: scores + inv norms + per-block (sum, ssq) partials. (proven r0)
__global__ void k_scores(const float* __restrict__ K,
                         const float* __restrict__ pvec,
                         float* __restrict__ svals,
                         float* __restrict__ invn,
                         float2* __restrict__ pstat) {
    __shared__ float4 p4s[256];
    __shared__ float wsum[4], wssq[4];
    int t = threadIdx.x;
    p4s[t] = ((const float4*)pvec)[t];
    __syncthreads();
    int wave = t >> 6, lane = t & 63;
    int row0 = blockIdx.x * 16 + wave * 4;
    const float4* k4 = (const float4*)K + (size_t)row0 * 256;
    float d0 = 0, d1 = 0, d2 = 0, d3 = 0;
    float q0 = 0, q1 = 0, q2 = 0, q3 = 0;
    #pragma unroll
    for (int i = 0; i < 4; ++i) {
        int idx = lane + i * 64;
        float4 p = p4s[idx];
        float4 a = k4[idx];
        float4 b = k4[256 + idx];
        float4 c = k4[512 + idx];
        float4 e = k4[768 + idx];
        d0 += a.x * p.x + a.y * p.y + a.z * p.z + a.w * p.w;
        q0 += a.x * a.x + a.y * a.y + a.z * a.z + a.w * a.w;
        d1 += b.x * p.x + b.y * p.y + b.z * p.z + b.w * p.w;
        q1 += b.x * b.x + b.y * b.y + b.z * b.z + b.w * b.w;
        d2 += c.x * p.x + c.y * p.y + c.z * p.z + c.w * p.w;
        q2 += c.x * c.x + c.y * c.y + c.z * c.z + c.w * c.w;
        d3 += e.x * p.x + e.y * p.y + e.z * p.z + e.w * p.w;
        q3 += e.x * e.x + e.y * e.y + e.z * e.z + e.w * e.w;
    }
    #pragma unroll
    for (int o = 32; o > 0; o >>= 1) {
        d0 += __shfl_down(d0, o); q0 += __shfl_down(q0, o);
        d1 += __shfl_down(d1, o); q1 += __shfl_down(q1, o);
        d2 += __shfl_down(d2, o); q2 += __shfl_down(q2, o);
        d3 += __shfl_down(d3, o); q3 += __shfl_down(q3, o);
    }
    if (lane == 0) {
        float i0 = 1.0f / fmaxf(sqrtf(q0), 1e-12f);
        float i1 = 1.0f / fmaxf(sqrtf(q1), 1e-12f);
        float i2 = 1.0f / fmaxf(sqrtf(q2), 1e-12f);
        float i3 = 1.0f / fmaxf(sqrtf(q3), 1e-12f);
        float s0 = d0 * i0, s1 = d1 * i1, s2 = d2 * i2, s3 = d3 * i3;
        float4 sv = make_float4(s0, s1, s2, s3);
        float4 iv = make_float4(i0, i1, i2, i3);
        *(float4*)(svals + row0) = sv;
        *(float4*)(invn + row0) = iv;
        wsum[wave] = s0 + s1 + s2 + s3;
        wssq[wave] = s0 * s0 + s1 * s1 + s2 * s2 + s3 * s3;
    }
    __syncthreads();
    if (t == 0)
        pstat[blockIdx.x] = make_float2(wsum[0] + wsum[1] + wsum[2] + wsum[3],
                                        wssq[0] + wssq[1] + wssq[2] + wssq[3]);
}

// Pass 2 MERGED: redundant global stats (32 KB pstat, L2-hot) + own-64-row
// coeff in LDS + per-block esum partial + weighted K column-sum -> pw.
// 1024 blocks x 256 thr. Removes the k_coeff dispatch + coeff array round-trip.
__global__ void k_wsumc(const float* __restrict__ K,
                        const float* __restrict__ svals,
                        const float* __restrict__ invn,
                        const float2* __restrict__ pstat,
                        float* __restrict__ pw,
                        float* __restrict__ esum) {
    __shared__ float rs[256], rq[256];
    __shared__ float cf[64];
    int t = threadIdx.x, b = blockIdx.x;
    float s = 0.f, q = 0.f;
    for (int i = t; i < SBLK; i += 256) {
        float2 p = pstat[i];
        s += p.x; q += p.y;
    }
    rs[t] = s; rq[t] = q;
    __syncthreads();
    for (int k = 128; k > 0; k >>= 1) {
        if (t < k) { rs[t] += rs[t + k]; rq[t] += rq[t + k]; }
        __syncthreads();
    }
    float mean = rs[0] / (float)NROWS;
    float var  = (rq[0] - (float)NROWS * mean * mean) / (float)(NROWS - 1);
    float rstd = 1.0f / (sqrtf(fmaxf(var, 0.0f)) + 1e-8f);
    int r0 = b * 64;
    if (t < 64) {   // wave 0 computes the block's 64 coefficients
        float z = (svals[r0 + t] - mean) * rstd;
        z = fminf(fmaxf(z, -10.0f), 10.0f);
        float e = expf(z);
        cf[t] = e * invn[r0 + t];
        float es = e;
        #pragma unroll
        for (int o = 32; o > 0; o >>= 1) es += __shfl_down(es, o);
        if (t == 0) esum[b] = es;
    }
    __syncthreads();
    const float4* M4 = (const float4*)K + (size_t)r0 * 256 + t;
    float4 acc = make_float4(0.f, 0.f, 0.f, 0.f);
    #pragma unroll 16
    for (int r = 0; r < 64; ++r) {
        float c = cf[r];
        float4 m = M4[(size_t)r * 256];
        acc.x += c * m.x; acc.y += c * m.y; acc.z += c * m.z; acc.w += c * m.w;
    }
    ((float4*)pw)[(size_t)b * 256 + t] = acc;
}

// Fold WBLK=1024 partials + reduce esum[WBLK] -> wacc = w / sum(exp).
// 32 blocks x 256 thr (was 4 blocks: 1/64 of the chip — parallelism bug).
// Block b owns 8 float4-columns; thread t: col co=t&7, row-group rg=t>>3
// covering rows [rg*32, rg*32+32).
__global__ void k_wred2(const float* __restrict__ pw,
                        const float* __restrict__ esum,
                        float* __restrict__ wacc) {
    __shared__ float  rs[256];
    __shared__ float4 sh4[256];
    int t = threadIdx.x, b = blockIdx.x;
    float es = 0.f;
    #pragma unroll
    for (int i = 0; i < 4; ++i) es += esum[t + i * 256];
    rs[t] = es;
    __syncthreads();
    for (int k = 128; k > 0; k >>= 1) {
        if (t < k) rs[t] += rs[t + k];
        __syncthreads();
    }
    float inv = 1.0f / rs[0];
    const float4* pw4 = (const float4*)pw;
    int co = t & 7, rg = t >> 3;
    int c4 = b * 8 + co;
    float4 acc = make_float4(0.f, 0.f, 0.f, 0.f);
    #pragma unroll 8
    for (int r = rg * 32; r < rg * 32 + 32; ++r) {
        float4 m = pw4[(size_t)r * 256 + c4];
        acc.x += m.x; acc.y += m.y; acc.z += m.z; acc.w += m.w;
    }
    sh4[t] = acc;
    __syncthreads();
    for (int s = 16; s > 0; s >>= 1) {
        if (rg < s) {
            sh4[t].x += sh4[t + s * 8].x; sh4[t].y += sh4[t + s * 8].y;
            sh4[t].z += sh4[t + s * 8].z; sh4[t].w += sh4[t + s * 8].w;
        }
        __syncthreads();
    }
    if (t < 8) {
        float4 w = sh4[t];
        ((float4*)wacc)[b * 8 + t] =
            make_float4(w.x * inv, w.y * inv, w.z * inv, w.w * inv);
    }
}

// out[c4] = sum_r coeff[r] * M[r][c4]. (proven r0)
__global__ void k_matvec_col(const float* __restrict__ M,
                             const float* __restrict__ coeff,
                             const float* __restrict__ cbias,
                             float* __restrict__ out,
                             int nrows, int ncols4) {
    __shared__ float4 red[256];
    int t = threadIdx.x, c4 = blockIdx.x;
    const float4* M4 = (const float4*)M;
    float4 acc = make_float4(0.f, 0.f, 0.f, 0.f);
    for (int r = t; r < nrows; r += 256) {
        float c = coeff[r];
        if (cbias) c += cbias[r];
        float4 m = M4[(size_t)r * ncols4 + c4];
        acc.x += c * m.x; acc.y += c * m.y; acc.z += c * m.z; acc.w += c * m.w;
    }
    red[t] = acc;
    __syncthreads();
    for (int s = 128; s > 0; s >>= 1) {
        if (t < s) {
            red[t].x += red[t + s].x; red[t].y += red[t + s].y;
            red[t].z += red[t + s].z; red[t].w += red[t + s].w;
        }
        __syncthreads();
    }
    if (t == 0) ((float4*)out)[c4] = red[0];
}

// outacc = (ovacc + bv) @ Wm with sigmoid gate fused. 256 blocks. (proven r6)
__global__ void k_mv_final(const float* __restrict__ Wm,
                           const float* __restrict__ ovacc,
                           const float* __restrict__ bv,
                           const float* __restrict__ q_init,
                           const float* __restrict__ bm,
                           const float* __restrict__ gamma,
                           float* __restrict__ out) {
    __shared__ float4 sh4[256];
    int t = threadIdx.x, b = blockIdx.x;
    const float4* W4 = (const float4*)Wm;
    float4 acc = make_float4(0.f, 0.f, 0.f, 0.f);
    for (int r = t; r < DIM; r += 256) {
        float c = ovacc[r] + bv[r];
        float4 m = W4[(size_t)r * 256 + b];
        acc.x += c * m.x; acc.y += c * m.y; acc.z += c * m.z; acc.w += c * m.w;
    }
    sh4[t] = acc;
    __syncthreads();
    for (int s = 128; s > 0; s >>= 1) {
        if (t < s) {
            sh4[t].x += sh4[t + s].x; sh4[t].y += sh4[t + s].y;
            sh4[t].z += sh4[t + s].z; sh4[t].w += sh4[t + s].w;
        }
        __syncthreads();
    }
    if (t == 0) {
        float g = 1.0f / (1.0f + expf(-gamma[0]));
        float4 o  = sh4[0];
        float4 qi = ((const float4*)q_init)[b];
        float4 bb = ((const float4*)bm)[b];
        float4 res;
        res.x = g * qi.x + (1.0f - g) * (o.x + bb.x);
        res.y = g * qi.y + (1.0f - g) * (o.y + bb.y);
        res.z = g * qi.z + (1.0f - g) * (o.z + bb.z);
        res.w = g * qi.w + (1.0f - g) * (o.w + bb.w);
        ((float4*)out)[b] = res;
    }
}

extern "C" void kernel_launch(void* const* d_in, const int* in_sizes, int n_in,
                              void* d_out, int out_size, void* d_ws, size_t ws_size,
                              hipStream_t stream) {
    const float* q_init = (const float*)d_in[0];
    const float* k_init = (const float*)d_in[1];
    const float* Wq     = (const float*)d_in[2];
    const float* bq     = (const float*)d_in[3];
    const float* Wk     = (const float*)d_in[4];
    // d_in[5] = bk: constant shift of all scores -> cancels in standardization
    const float* Wv     = (const float*)d_in[6];
    const float* bv     = (const float*)d_in[7];
    const float* Wm     = (const float*)d_in[8];
    const float* bm     = (const float*)d_in[9];
    const float* gamma  = (const float*)d_in[10];
    float* out = (float*)d_out;
    float* ws  = (float*)d_ws;

    float*  qacc   = ws + OFF_QACC;
    float*  pvec   = ws + OFF_PVEC;
    float2* pstat  = (float2*)(ws + OFF_PSTAT);
    float*  svals  = ws + OFF_S;
    float*  invn   = ws + OFF_INVN;
    float*  esum   = ws + OFF_ESUM;
    float*  pw     = ws + OFF_PW;
    float*  wacc   = ws + OFF_WACC;
    float*  ovacc  = ws + OFF_OVACC;

    // 7 dispatches (was 8): coeff merged into pass-2; wred now 32 blocks
    k_q<<<HALF / 4, 256, 0, stream>>>(q_init, Wq, qacc);
    k_pvec<<<DIM / 4, 256, 0, stream>>>(Wk, qacc, bq, pvec);
    k_scores<<<SBLK, 256, 0, stream>>>(k_init, pvec, svals, invn, pstat);
    k_wsumc<<<WBLK, 256, 0, stream>>>(k_init, svals, invn, pstat, pw, esum);
    k_wred2<<<32, 256, 0, stream>>>(pw, esum, wacc);
    k_matvec_col<<<DIM / 4, 256, 0, stream>>>(Wv, wacc, nullptr, ovacc, DIM, DIM / 4);
    k_mv_final<<<DIM / 4, 256, 0, stream>>>(Wm, ovacc, bv, q_init, bm, gamma, out);
}